// Round 9
// baseline (134.601 us; speedup 1.0000x reference)
//
#include <hip/hip_runtime.h>

#define T_ 3
#define B_ 4
#define N_ 4096
#define K_ 8

#define KNN_BLOCKS (B_ * (N_ / 8))     // 2048 knn+arap role blocks (8 queries each)
#define CH_BLOCKS  (T_ * B_ * 2 * 16)  // 384 chamfer-MFMA role blocks
#define SL_BLOCKS  32                  // small-losses role blocks
#define KWIN 1024                      // knn candidate window
#define CWIN 512                       // chamfer candidate window

typedef short bf16x8 __attribute__((ext_vector_type(8)));
typedef float f32x4  __attribute__((ext_vector_type(4)));

// ---------------------------------------------------------------------------
template <int NW>
__device__ inline float block_reduce(float v, float* scratch) {
    #pragma unroll
    for (int off = 32; off > 0; off >>= 1) v += __shfl_down(v, off, 64);
    const int lane = threadIdx.x & 63, wid = threadIdx.x >> 6;
    if (lane == 0) scratch[wid] = v;
    __syncthreads();
    float s = 0.f;
    if (threadIdx.x == 0) {
        #pragma unroll
        for (int w = 0; w < NW; ++w) s += scratch[w];
    }
    return s;  // valid on thread 0 only
}

// Batcher odd-even 8-sort (19 CEs) — independent of running list (ILP).
#define CE_(A, i, j) { unsigned lo_ = min(A[i], A[j]); A[j] = max(A[i], A[j]); A[i] = lo_; }
__device__ inline void sort8(unsigned s[8]) {
    CE_(s,0,1) CE_(s,2,3) CE_(s,4,5) CE_(s,6,7)
    CE_(s,0,2) CE_(s,1,3) CE_(s,4,6) CE_(s,5,7)
    CE_(s,1,2) CE_(s,5,6)
    CE_(s,0,4) CE_(s,1,5) CE_(s,2,6) CE_(s,3,7)
    CE_(s,2,4) CE_(s,3,5)
    CE_(s,1,2) CE_(s,3,4) CE_(s,5,6)
}
// a (asc) := lowest-8 of union(a asc, s asc), sorted. Half-clean + bitonic merge.
__device__ inline void merge_top8(unsigned a[8], const unsigned s[8]) {
    #pragma unroll
    for (int i = 0; i < 8; ++i) a[i] = min(a[i], s[7 - i]);  // bitonic, lowest 8
    CE_(a,0,4) CE_(a,1,5) CE_(a,2,6) CE_(a,3,7)
    CE_(a,0,2) CE_(a,1,3) CE_(a,4,6) CE_(a,5,7)
    CE_(a,0,1) CE_(a,2,3) CE_(a,4,5) CE_(a,6,7)
}

// bf16 hi/lo split helpers (truncation; residual captures 8 more mantissa bits)
__device__ inline short hi16(float v) { return (short)(__float_as_uint(v) >> 16); }
__device__ inline float residual(float v) {
    return v - __uint_as_float(__float_as_uint(v) & 0xFFFF0000u);
}
__device__ inline unsigned pk2(short a, short b) {
    return (unsigned)(unsigned short)a | ((unsigned)(unsigned short)b << 16);
}
#define BF16_ONE ((short)0x3F80)

// ---------------------------------------------------------------------------
// Single mega kernel, three roles by blockIdx:
//   [0,2048)      KNN + fused ARAP: 8 queries/block, wave = query pair,
//                 64 lanes = 64 candidate residue classes (j == lane mod 64).
//                 Cross-class merge = 6-stage shfl_xor butterfly (no LDS).
//   [2048,2432)   chamfer via MFMA (hi/lo bf16 split, near-fp32 exact)
//   [2432,2464)   pd + sp + tran grid-stride
// Grid (2464) > residency cap (6/CU => 1536) on purpose: backfill balances
// the tail (KNN blocks ~2.5x longer than chamfer blocks).
__global__ __launch_bounds__(256, 6) void mega_kernel(const float* __restrict__ src,
                                                      const float* __restrict__ dp_all,
                                                      const float* __restrict__ tp,
                                                      const float* __restrict__ drp,
                                                      const float* __restrict__ pw,
                                                      const float* __restrict__ rm,
                                                      float* __restrict__ out) {
    __shared__ uint4 smem4[1024];  // 16 KiB, shared by all roles

    if (blockIdx.x < KNN_BLOCKS) {  // ================= KNN + ARAP role
        float4* win = (float4*)smem4;
        const int b  = blockIdx.x / (N_ / 8);
        const int q0 = (blockIdx.x % (N_ / 8)) * 8;
        const float* sb = src + (size_t)b * N_ * 3;

        const int wv = threadIdx.x >> 6;  // wave = query pair 0..3
        const int c  = threadIdx.x & 63;  // residue class = lane
        const int i0 = q0 + 2 * wv, i1 = i0 + 1;
        const float qx0 = sb[3 * i0], qy0 = sb[3 * i0 + 1], qz0 = sb[3 * i0 + 2];
        const float qx1 = sb[3 * i1], qy1 = sb[3 * i1 + 1], qz1 = sb[3 * i1 + 2];
        const float q20 = fmaf(qx0, qx0, fmaf(qy0, qy0, qz0 * qz0));
        const float q21 = fmaf(qx1, qx1, fmaf(qy1, qy1, qz1 * qz1));

        unsigned a0[K_], a1[K_];
        #pragma unroll
        for (int p = 0; p < K_; ++p) { a0[p] = 0xFFFFFFFFu; a1[p] = 0xFFFFFFFFu; }

        for (int w = 0; w < N_ / KWIN; ++w) {
            __syncthreads();
            for (int j = threadIdx.x; j < KWIN; j += 256) {
                int jg = w * KWIN + j;
                float x = sb[3 * jg], y = sb[3 * jg + 1], z = sb[3 * jg + 2];
                win[j] = make_float4(-2.f * x, -2.f * y, -2.f * z,
                                     fmaf(x, x, fmaf(y, y, z * z)));
            }
            __syncthreads();

            #pragma unroll
            for (int bt = 0; bt < KWIN / 8 / 64; ++bt) {  // 2 batches of 8
                unsigned s0[8], s1[8];
                #pragma unroll
                for (int u = 0; u < 8; ++u) {
                    int jl = 64 * (bt * 8 + u) + c;   // consecutive across lanes
                    float4 cd = win[jl];
                    int jglob = w * KWIN + jl;
                    float d0 = fmaf(qx0, cd.x, fmaf(qy0, cd.y, fmaf(qz0, cd.z, cd.w))) + q20;
                    float d1 = fmaf(qx1, cd.x, fmaf(qy1, cd.y, fmaf(qz1, cd.z, cd.w))) + q21;
                    unsigned p0 = (__float_as_uint(d0) & 0xFFFFF000u) | (unsigned)jglob;
                    unsigned p1 = (__float_as_uint(d1) & 0xFFFFF000u) | (unsigned)jglob;
                    s0[u] = (jglob == i0) ? 0xFFFFFFFFu : p0;  // exclude self
                    s1[u] = (jglob == i1) ? 0xFFFFFFFFu : p1;
                }
                sort8(s0); merge_top8(a0, s0);
                sort8(s1); merge_top8(a1, s1);
            }
        }

        // Cross-class merge: 6-stage butterfly over the 64 lanes via shfl_xor.
        // merge_top8 folds multisets, so after 6 stages every lane holds the
        // global top-8 for its wave's two queries.
        #pragma unroll
        for (int mask = 32; mask >= 1; mask >>= 1) {
            unsigned t0[8], t1[8];
            #pragma unroll
            for (int e = 0; e < K_; ++e) {
                t0[e] = __shfl_xor(a0[e], mask, 64);
                t1[e] = __shfl_xor(a1[e], mask, 64);
            }
            merge_top8(a0, t0);
            merge_top8(a1, t1);
        }

        // Publish 8 queries x 8 neighbor indices, then fused ARAP.
        __syncthreads();  // window reads done before smem reuse
        unsigned* nidx = (unsigned*)smem4 + 64;  // 64 entries
        if (c == 0) {
            #pragma unroll
            for (int e = 0; e < K_; ++e) {
                nidx[(2 * wv) * K_ + e]     = a0[e] & 0xFFFu;
                nidx[(2 * wv + 1) * K_ + e] = a1[e] & 0xFFFu;
            }
        }
        __syncthreads();

        float acc = 0.f;
        if (threadIdx.x < 8 * K_) {
            const int q  = threadIdx.x >> 3;
            const int qi = q0 + q;
            const int j  = (int)nidx[threadIdx.x];
            float sx = sb[3 * qi], sy = sb[3 * qi + 1], sz = sb[3 * qi + 2];
            float ex = sb[3 * j] - sx, ey = sb[3 * j + 1] - sy, ez = sb[3 * j + 2] - sz;
            float sd = sqrtf(fmaf(ex, ex, fmaf(ey, ey, ez * ez)) + 1e-5f);
            #pragma unroll
            for (int t = 0; t < T_; ++t) {
                const float* dpb = dp_all + ((size_t)(t * B_ + b)) * N_ * 3;
                float dx = dpb[3 * j] - dpb[3 * qi];
                float dy = dpb[3 * j + 1] - dpb[3 * qi + 1];
                float dz = dpb[3 * j + 2] - dpb[3 * qi + 2];
                float dd = sqrtf(fmaf(dx, dx, fmaf(dy, dy, dz * dz)) + 1e-5f);
                float df = dd - sd;
                acc = fmaf(df, df, acc);
            }
        }
        float s = block_reduce<4>(acc, (float*)smem4);
        if (threadIdx.x == 0) atomicAdd(out, s * (1.0f / B_));

    } else if (blockIdx.x < KNN_BLOCKS + CH_BLOCKS) {  // ========= chamfer role
        uint4* alds = smem4;  // A-frags: [tile(32)][quad(2)][m(16)] uint4
        const int cb   = blockIdx.x - KNN_BLOCKS;
        const int tbd  = cb >> 4;     // ((t*B+b)*2+dir)
        const int slab = cb & 15;     // 256-query slab
        const int dir = tbd & 1;
        const int tb  = tbd >> 1;
        const int b = tb % B_, t = tb / B_;

        const float* dpb = dp_all + ((size_t)(t * B_ + b)) * N_ * 3;
        const float* tpb = tp + (size_t)b * N_ * 3;
        const float* cbase = dir ? dpb : tpb;  // candidates
        const float* qbase = dir ? tpb : dpb;  // queries

        const int lane = threadIdx.x & 63;
        const int wave = threadIdx.x >> 6;
        const int quad = lane >> 4;
        const int n    = lane & 15;

        bf16x8 bfrag[4];
        float  q2r[4];
        #pragma unroll
        for (int s = 0; s < 4; ++s) {
            int qid = slab * 256 + wave * 64 + s * 16 + n;
            float x = qbase[3 * qid], y = qbase[3 * qid + 1], z = qbase[3 * qid + 2];
            q2r[s] = fmaf(x, x, fmaf(y, y, z * z));
            short hx = hi16(x), hy = hi16(y), hz = hi16(z);
            short lx = hi16(residual(x)), ly = hi16(residual(y)), lz = hi16(residual(z));
            if (quad == 0)
                bfrag[s] = (bf16x8){hx, hy, hz, hx, hy, hz, BF16_ONE, BF16_ONE};
            else if (quad == 1)
                bfrag[s] = (bf16x8){lx, ly, lz, lx, ly, lz, 0, 0};
            else
                bfrag[s] = (bf16x8)(short)0;  // k=16..31 zero-pad
        }

        float run[4] = {3.4e38f, 3.4e38f, 3.4e38f, 3.4e38f};
        const f32x4 zero4 = {0.f, 0.f, 0.f, 0.f};

        for (int w = 0; w < N_ / CWIN; ++w) {
            __syncthreads();
            // Staging with jloc consecutive across lanes -> <=2-way bank alias.
            #pragma unroll
            for (int r = 0; r < 2; ++r) {
                int jloc = r * 256 + threadIdx.x;
                int jg = w * CWIN + jloc;
                float x = cbase[3 * jg], y = cbase[3 * jg + 1], z = cbase[3 * jg + 2];
                float p2 = fmaf(x, x, fmaf(y, y, z * z));
                float mx = -2.f * x, my = -2.f * y, mz = -2.f * z;
                short mhx = hi16(mx), mhy = hi16(my), mhz = hi16(mz);
                short mlx = hi16(residual(mx)), mly = hi16(residual(my)), mlz = hi16(residual(mz));
                short p2h = hi16(p2), p2l = hi16(residual(p2));
                uint4 f0 = make_uint4(pk2(mhx, mhy), pk2(mhz, mlx), pk2(mly, mlz), pk2(p2h, p2l));
                uint4 f1 = make_uint4(f0.x, f0.y, f0.z, 0u);
                int tile = jloc >> 4, m = jloc & 15;
                alds[tile * 32 + m]      = f0;  // quad 0 slice (k0-7)
                alds[tile * 32 + 16 + m] = f1;  // quad 1 slice (k8-15)
            }
            __syncthreads();

            #pragma unroll 4
            for (int tile = 0; tile < CWIN / 16; ++tile) {
                bf16x8 af = (bf16x8)(short)0;
                if (quad < 2) {
                    union { uint4 u; bf16x8 v; } cv;
                    cv.u = alds[tile * 32 + quad * 16 + n];
                    af = cv.v;
                }
                #pragma unroll
                for (int s = 0; s < 4; ++s) {
                    f32x4 d = __builtin_amdgcn_mfma_f32_16x16x32_bf16(af, bfrag[s], zero4, 0, 0, 0);
                    float r3 = fminf(fminf(d[0], d[1]), d[2]);
                    run[s] = fminf(fminf(run[s], r3), d[3]);
                }
            }
        }

        float vsum = 0.f;
        #pragma unroll
        for (int s = 0; s < 4; ++s) {
            float r = run[s];
            r = fminf(r, __shfl_xor(r, 32));
            r = fminf(r, __shfl_xor(r, 16));
            if (lane < 16) vsum += r + q2r[s];
        }
        __syncthreads();  // alds reads done before reusing smem as scratch
        float ssum = block_reduce<4>(vsum, (float*)smem4);
        if (threadIdx.x == 0) atomicAdd(out, ssum * (0.5f / B_));

    } else {  // ================= pd + sp + tran role
        const int PD_N = T_ * B_ * N_ * 3;
        const int SP_N = T_ * B_ * N_;
        const int stride = SL_BLOCKS * 256;
        const int gid = (blockIdx.x - KNN_BLOCKS - CH_BLOCKS) * 256 + threadIdx.x;
        float apd = 0.f;
        for (int i = gid; i < PD_N; i += stride) {
            float d = drp[i] - dp_all[i];
            apd = fmaf(d, d, apd);
        }
        float asp = 0.f;
        for (int i = gid; i < SP_N; i += stride) asp += fabsf(pw[i]);
        float atr = 0.f;
        if (gid < T_ * B_ * 3) {
            int t = gid / (B_ * 3);
            int b = (gid / 3) % B_;
            int r = gid % 3;
            float v = rm[t * B_ * 16 + b * 16 + r * 4 + 3];
            atr = v * v;
        }
        float acc = apd * (1.0f / B_) + asp * (1.0f / (B_ * N_)) + atr * (1.0f / B_);
        float s = block_reduce<4>(acc, (float*)smem4);
        if (threadIdx.x == 0) atomicAdd(out, s);
    }
}

// ---------------------------------------------------------------------------
extern "C" void kernel_launch(void* const* d_in, const int* in_sizes, int n_in,
                              void* d_out, int out_size, void* d_ws, size_t ws_size,
                              hipStream_t stream) {
    const float* pw  = (const float*)d_in[1];
    const float* drp = (const float*)d_in[2];
    const float* dp  = (const float*)d_in[3];
    const float* rm  = (const float*)d_in[4];
    const float* sp  = (const float*)d_in[5];
    const float* tp  = (const float*)d_in[6];
    float* out = (float*)d_out;

    hipMemsetAsync(out, 0, sizeof(float), stream);
    mega_kernel<<<KNN_BLOCKS + CH_BLOCKS + SL_BLOCKS, 256, 0, stream>>>(
        sp, dp, tp, drp, pw, rm, out);
}

// Round 10
// 124.582 us; speedup vs baseline: 1.0804x; 1.0804x over previous
//
#include <hip/hip_runtime.h>

#define T_ 3
#define B_ 4
#define N_ 4096
#define K_ 8

#define KNN_BLOCKS (B_ * (N_ / 16))    // 1024 knn+arap role blocks (16 q each)
#define CH_BLOCKS  (T_ * B_ * 2 * 16)  // 384 chamfer-MFMA role blocks
#define SL_BLOCKS  32                  // small-losses role blocks
#define CWIN 512                       // candidate window (16 KiB A-frags)

typedef short bf16x8 __attribute__((ext_vector_type(8)));
typedef float f32x4  __attribute__((ext_vector_type(4)));

// ---------------------------------------------------------------------------
template <int NW>
__device__ inline float block_reduce(float v, float* scratch) {
    #pragma unroll
    for (int off = 32; off > 0; off >>= 1) v += __shfl_down(v, off, 64);
    const int lane = threadIdx.x & 63, wid = threadIdx.x >> 6;
    if (lane == 0) scratch[wid] = v;
    __syncthreads();
    float s = 0.f;
    if (threadIdx.x == 0) {
        #pragma unroll
        for (int w = 0; w < NW; ++w) s += scratch[w];
    }
    return s;  // valid on thread 0 only
}

// Batcher odd-even 8-sort (19 CEs) — independent of running list (ILP).
#define CE_(A, i, j) { unsigned lo_ = min(A[i], A[j]); A[j] = max(A[i], A[j]); A[i] = lo_; }
__device__ inline void sort8(unsigned s[8]) {
    CE_(s,0,1) CE_(s,2,3) CE_(s,4,5) CE_(s,6,7)
    CE_(s,0,2) CE_(s,1,3) CE_(s,4,6) CE_(s,5,7)
    CE_(s,1,2) CE_(s,5,6)
    CE_(s,0,4) CE_(s,1,5) CE_(s,2,6) CE_(s,3,7)
    CE_(s,2,4) CE_(s,3,5)
    CE_(s,1,2) CE_(s,3,4) CE_(s,5,6)
}
// a (asc) := lowest-8 of union(a asc, s asc), sorted. Half-clean + bitonic merge.
__device__ inline void merge_top8(unsigned a[8], const unsigned s[8]) {
    #pragma unroll
    for (int i = 0; i < 8; ++i) a[i] = min(a[i], s[7 - i]);  // bitonic, lowest 8
    CE_(a,0,4) CE_(a,1,5) CE_(a,2,6) CE_(a,3,7)
    CE_(a,0,2) CE_(a,1,3) CE_(a,4,6) CE_(a,5,7)
    CE_(a,0,1) CE_(a,2,3) CE_(a,4,5) CE_(a,6,7)
}

// bf16 hi/lo split helpers (truncation; residual captures 8 more mantissa bits)
__device__ inline short hi16(float v) { return (short)(__float_as_uint(v) >> 16); }
__device__ inline float residual(float v) {
    return v - __uint_as_float(__float_as_uint(v) & 0xFFFF0000u);
}
__device__ inline unsigned pk2(short a, short b) {
    return (unsigned)(unsigned short)a | ((unsigned)(unsigned short)b << 16);
}
#define BF16_ONE ((short)0x3F80)

// ---------------------------------------------------------------------------
// Single mega kernel, three roles by blockIdx:
//   [0,1024)      KNN(+ARAP) via MFMA: D[m=cand][n=query] = |c|^2 - 2c.q + |q|^2
//                 (hi/lo bf16 split; k6/7: |c|^2 * 1, k14/15: 1 * |q|^2 => d>=0,
//                 so raw float bits are sort-monotone). VALU does only the
//                 branch-free top-8 selection on packed (distbits|index) keys.
//   [1024,1408)   chamfer via MFMA (as r7-r9, conflict-free staging)
//   [1408,1440)   pd + sp + tran grid-stride
__global__ __launch_bounds__(256, 6) void mega_kernel(const float* __restrict__ src,
                                                      const float* __restrict__ dp_all,
                                                      const float* __restrict__ tp,
                                                      const float* __restrict__ drp,
                                                      const float* __restrict__ pw,
                                                      const float* __restrict__ rm,
                                                      float* __restrict__ out) {
    __shared__ uint4 smem4[1024];  // 16 KiB, shared by all roles
    const f32x4 zero4 = {0.f, 0.f, 0.f, 0.f};

    if (blockIdx.x < KNN_BLOCKS) {  // ================= KNN + ARAP role (MFMA)
        uint4* alds = smem4;  // A-frags: [tile(32)][quad(2)][m(16)] uint4
        const int b   = blockIdx.x / (N_ / 16);
        const int qt0 = (blockIdx.x % (N_ / 16)) * 16;  // 16 queries/block
        const float* sb = src + (size_t)b * N_ * 3;

        const int wid  = __builtin_amdgcn_readfirstlane(threadIdx.x >> 6);
        const int lane = threadIdx.x & 63;
        const int n    = lane & 15;   // query col (and A-row m for staging reads)
        const int quad = lane >> 4;
        const int rbase = quad * 4;   // D-row base (candidate offset in tile)
        const int qid  = qt0 + n;

        // B-frag: this lane's query, hi/lo split; |q|^2 injected at k14/k15.
        bf16x8 bfrag = (bf16x8)(short)0;
        {
            float x = sb[3 * qid], y = sb[3 * qid + 1], z = sb[3 * qid + 2];
            float q2 = fmaf(x, x, fmaf(y, y, z * z));
            short hx = hi16(x), hy = hi16(y), hz = hi16(z);
            short lx = hi16(residual(x)), ly = hi16(residual(y)), lz = hi16(residual(z));
            if (quad == 0) bfrag = (bf16x8){hx, hy, hz, hx, hy, hz, BF16_ONE, BF16_ONE};
            else if (quad == 1) bfrag = (bf16x8){lx, ly, lz, lx, ly, lz,
                                                 hi16(q2), hi16(residual(q2))};
        }

        unsigned a[K_];
        #pragma unroll
        for (int p = 0; p < K_; ++p) a[p] = 0xFFFFFFFFu;

        for (int w = 0; w < N_ / CWIN; ++w) {  // 8 windows of 512 candidates
            __syncthreads();
            // Stage A-frags (2 candidates/thread, consecutive -> conflict-free).
            #pragma unroll
            for (int r = 0; r < 2; ++r) {
                int jloc = r * 256 + threadIdx.x;
                int jg = w * CWIN + jloc;
                float x = sb[3 * jg], y = sb[3 * jg + 1], z = sb[3 * jg + 2];
                float p2 = fmaf(x, x, fmaf(y, y, z * z));
                float mx = -2.f * x, my = -2.f * y, mz = -2.f * z;
                short mhx = hi16(mx), mhy = hi16(my), mhz = hi16(mz);
                short mlx = hi16(residual(mx)), mly = hi16(residual(my)), mlz = hi16(residual(mz));
                uint4 f0 = make_uint4(pk2(mhx, mhy), pk2(mhz, mlx), pk2(mly, mlz),
                                      pk2(hi16(p2), hi16(residual(p2))));
                uint4 f1 = make_uint4(f0.x, f0.y, f0.z, pk2(BF16_ONE, BF16_ONE));
                int tile = jloc >> 4, m = jloc & 15;
                alds[tile * 32 + m]      = f0;  // k0-7 slice
                alds[tile * 32 + 16 + m] = f1;  // k8-15 slice
            }
            __syncthreads();

            // This wave's quarter: tiles wid*8 .. wid*8+7 (batches of 2 tiles).
            #pragma unroll
            for (int bt = 0; bt < 4; ++bt) {
                unsigned s8[8];
                #pragma unroll
                for (int h = 0; h < 2; ++h) {
                    const int tile = wid * 8 + bt * 2 + h;
                    const int tbg  = w * CWIN + tile * 16;  // 16-aligned
                    bf16x8 af = (bf16x8)(short)0;
                    if (quad < 2) {
                        union { uint4 u; bf16x8 v; } cv;
                        cv.u = alds[tile * 32 + quad * 16 + n];
                        af = cv.v;
                    }
                    f32x4 d = __builtin_amdgcn_mfma_f32_16x16x32_bf16(af, bfrag, zero4, 0, 0, 0);
                    #pragma unroll
                    for (int r = 0; r < 4; ++r)  // idx bits (0-11) disjoint from tbg
                        s8[h * 4 + r] = (__float_as_uint(d[r]) & 0xFFFFF000u)
                                        | (unsigned)(tbg | (rbase + r));
                    if (tbg == qt0) {  // wave-uniform: the one self-overlap tile
                        #pragma unroll
                        for (int r = 0; r < 4; ++r)
                            if (rbase + r == n) s8[h * 4 + r] = 0xFFFFFFFFu;
                    }
                }
                sort8(s8);
                merge_top8(a, s8);
            }
        }

        // Fold the 4 row-quads of each query column (lanes n, n+16, n+32, n+48).
        #pragma unroll
        for (int mk = 16; mk <= 32; mk <<= 1) {
            unsigned t[8];
            #pragma unroll
            for (int e = 0; e < K_; ++e) t[e] = __shfl_xor(a[e], mk, 64);
            merge_top8(a, t);
        }

        // Cross-wave merge (4 partial lists per query) + publish indices.
        __syncthreads();  // A-frag reads done; reuse LDS
        unsigned* sm = (unsigned*)smem4;          // [wave*16+q]*9+e  (<576)
        unsigned* nidx = (unsigned*)smem4 + 1024; // 128 entries
        if (lane < 16) {
            #pragma unroll
            for (int e = 0; e < K_; ++e) sm[(wid * 16 + n) * 9 + e] = a[e];
        }
        __syncthreads();
        if (threadIdx.x < 16) {
            const int q = threadIdx.x;
            unsigned md[K_];
            #pragma unroll
            for (int e = 0; e < K_; ++e) md[e] = sm[q * 9 + e];
            #pragma unroll
            for (int wv = 1; wv < 4; ++wv) {
                unsigned t[8];
                #pragma unroll
                for (int e = 0; e < K_; ++e) t[e] = sm[(wv * 16 + q) * 9 + e];
                merge_top8(md, t);
            }
            #pragma unroll
            for (int e = 0; e < K_; ++e) nidx[q * 8 + e] = md[e] & 0xFFFu;
        }
        __syncthreads();

        // Fused ARAP: 128 threads = 16 queries x 8 neighbors, all 3 t stages.
        float acc = 0.f;
        if (threadIdx.x < 16 * K_) {
            const int q  = threadIdx.x >> 3;
            const int qi = qt0 + q;
            const int j  = (int)nidx[threadIdx.x];
            float sx = sb[3 * qi], sy = sb[3 * qi + 1], sz = sb[3 * qi + 2];
            float ex = sb[3 * j] - sx, ey = sb[3 * j + 1] - sy, ez = sb[3 * j + 2] - sz;
            float sd = sqrtf(fmaf(ex, ex, fmaf(ey, ey, ez * ez)) + 1e-5f);
            #pragma unroll
            for (int t = 0; t < T_; ++t) {
                const float* dpb = dp_all + ((size_t)(t * B_ + b)) * N_ * 3;
                float dx = dpb[3 * j] - dpb[3 * qi];
                float dy = dpb[3 * j + 1] - dpb[3 * qi + 1];
                float dz = dpb[3 * j + 2] - dpb[3 * qi + 2];
                float dd = sqrtf(fmaf(dx, dx, fmaf(dy, dy, dz * dz)) + 1e-5f);
                float df = dd - sd;
                acc = fmaf(df, df, acc);
            }
        }
        float s = block_reduce<4>(acc, (float*)smem4);
        if (threadIdx.x == 0) atomicAdd(out, s * (1.0f / B_));

    } else if (blockIdx.x < KNN_BLOCKS + CH_BLOCKS) {  // ========= chamfer role
        uint4* alds = smem4;
        const int cb   = blockIdx.x - KNN_BLOCKS;
        const int tbd  = cb >> 4;     // ((t*B+b)*2+dir)
        const int slab = cb & 15;     // 256-query slab
        const int dir = tbd & 1;
        const int tb  = tbd >> 1;
        const int b = tb % B_, t = tb / B_;

        const float* dpb = dp_all + ((size_t)(t * B_ + b)) * N_ * 3;
        const float* tpb = tp + (size_t)b * N_ * 3;
        const float* cbase = dir ? dpb : tpb;  // candidates
        const float* qbase = dir ? tpb : dpb;  // queries

        const int lane = threadIdx.x & 63;
        const int wave = threadIdx.x >> 6;
        const int quad = lane >> 4;
        const int n    = lane & 15;

        bf16x8 bfrag[4];
        float  q2r[4];
        #pragma unroll
        for (int s = 0; s < 4; ++s) {
            int qid = slab * 256 + wave * 64 + s * 16 + n;
            float x = qbase[3 * qid], y = qbase[3 * qid + 1], z = qbase[3 * qid + 2];
            q2r[s] = fmaf(x, x, fmaf(y, y, z * z));
            short hx = hi16(x), hy = hi16(y), hz = hi16(z);
            short lx = hi16(residual(x)), ly = hi16(residual(y)), lz = hi16(residual(z));
            if (quad == 0)
                bfrag[s] = (bf16x8){hx, hy, hz, hx, hy, hz, BF16_ONE, BF16_ONE};
            else if (quad == 1)
                bfrag[s] = (bf16x8){lx, ly, lz, lx, ly, lz, 0, 0};
            else
                bfrag[s] = (bf16x8)(short)0;
        }

        float run[4] = {3.4e38f, 3.4e38f, 3.4e38f, 3.4e38f};

        for (int w = 0; w < N_ / CWIN; ++w) {
            __syncthreads();
            #pragma unroll
            for (int r = 0; r < 2; ++r) {
                int jloc = r * 256 + threadIdx.x;  // consecutive -> conflict-free
                int jg = w * CWIN + jloc;
                float x = cbase[3 * jg], y = cbase[3 * jg + 1], z = cbase[3 * jg + 2];
                float p2 = fmaf(x, x, fmaf(y, y, z * z));
                float mx = -2.f * x, my = -2.f * y, mz = -2.f * z;
                short mhx = hi16(mx), mhy = hi16(my), mhz = hi16(mz);
                short mlx = hi16(residual(mx)), mly = hi16(residual(my)), mlz = hi16(residual(mz));
                uint4 f0 = make_uint4(pk2(mhx, mhy), pk2(mhz, mlx), pk2(mly, mlz),
                                      pk2(hi16(p2), hi16(residual(p2))));
                uint4 f1 = make_uint4(f0.x, f0.y, f0.z, 0u);
                int tile = jloc >> 4, m = jloc & 15;
                alds[tile * 32 + m]      = f0;
                alds[tile * 32 + 16 + m] = f1;
            }
            __syncthreads();

            #pragma unroll 4
            for (int tile = 0; tile < CWIN / 16; ++tile) {
                bf16x8 af = (bf16x8)(short)0;
                if (quad < 2) {
                    union { uint4 u; bf16x8 v; } cv;
                    cv.u = alds[tile * 32 + quad * 16 + n];
                    af = cv.v;
                }
                #pragma unroll
                for (int s = 0; s < 4; ++s) {
                    f32x4 d = __builtin_amdgcn_mfma_f32_16x16x32_bf16(af, bfrag[s], zero4, 0, 0, 0);
                    float r3 = fminf(fminf(d[0], d[1]), d[2]);
                    run[s] = fminf(fminf(run[s], r3), d[3]);
                }
            }
        }

        float vsum = 0.f;
        #pragma unroll
        for (int s = 0; s < 4; ++s) {
            float r = run[s];
            r = fminf(r, __shfl_xor(r, 32));
            r = fminf(r, __shfl_xor(r, 16));
            if (lane < 16) vsum += r + q2r[s];
        }
        __syncthreads();
        float ssum = block_reduce<4>(vsum, (float*)smem4);
        if (threadIdx.x == 0) atomicAdd(out, ssum * (0.5f / B_));

    } else {  // ================= pd + sp + tran role
        const int PD_N = T_ * B_ * N_ * 3;
        const int SP_N = T_ * B_ * N_;
        const int stride = SL_BLOCKS * 256;
        const int gid = (blockIdx.x - KNN_BLOCKS - CH_BLOCKS) * 256 + threadIdx.x;
        float apd = 0.f;
        for (int i = gid; i < PD_N; i += stride) {
            float d = drp[i] - dp_all[i];
            apd = fmaf(d, d, apd);
        }
        float asp = 0.f;
        for (int i = gid; i < SP_N; i += stride) asp += fabsf(pw[i]);
        float atr = 0.f;
        if (gid < T_ * B_ * 3) {
            int t = gid / (B_ * 3);
            int b = (gid / 3) % B_;
            int r = gid % 3;
            float v = rm[t * B_ * 16 + b * 16 + r * 4 + 3];
            atr = v * v;
        }
        float acc = apd * (1.0f / B_) + asp * (1.0f / (B_ * N_)) + atr * (1.0f / B_);
        float s = block_reduce<4>(acc, (float*)smem4);
        if (threadIdx.x == 0) atomicAdd(out, s);
    }
}

// ---------------------------------------------------------------------------
extern "C" void kernel_launch(void* const* d_in, const int* in_sizes, int n_in,
                              void* d_out, int out_size, void* d_ws, size_t ws_size,
                              hipStream_t stream) {
    const float* pw  = (const float*)d_in[1];
    const float* drp = (const float*)d_in[2];
    const float* dp  = (const float*)d_in[3];
    const float* rm  = (const float*)d_in[4];
    const float* sp  = (const float*)d_in[5];
    const float* tp  = (const float*)d_in[6];
    float* out = (float*)d_out;

    hipMemsetAsync(out, 0, sizeof(float), stream);
    mega_kernel<<<KNN_BLOCKS + CH_BLOCKS + SL_BLOCKS, 256, 0, stream>>>(
        sp, dp, tp, drp, pw, rm, out);
}

// Round 11
// 122.197 us; speedup vs baseline: 1.1015x; 1.0195x over previous
//
#include <hip/hip_runtime.h>

#define T_ 3
#define B_ 4
#define N_ 4096
#define K_ 8

// Role interleave: 32 groups of 45 blocks = 32 KNN + 12 chamfer + 1 SL each.
// Uniform role mix across the dispatch stream keeps MFMA-heavy (chamfer) and
// VALU-heavy (KNN selection) waves co-resident on every CU for the whole
// kernel (m114: separate pipes co-schedule; r10's contiguous ranges ran as
// two serial phases at ~52% VALU).
#define GROUPS 32
#define GRP_KNN 32
#define GRP_CH  12
#define GRP_SZ  45  // 32 + 12 + 1
#define CWIN 512    // candidate window (16 KiB A-frags)

typedef short bf16x8 __attribute__((ext_vector_type(8)));
typedef float f32x4  __attribute__((ext_vector_type(4)));

// ---------------------------------------------------------------------------
template <int NW>
__device__ inline float block_reduce(float v, float* scratch) {
    #pragma unroll
    for (int off = 32; off > 0; off >>= 1) v += __shfl_down(v, off, 64);
    const int lane = threadIdx.x & 63, wid = threadIdx.x >> 6;
    if (lane == 0) scratch[wid] = v;
    __syncthreads();
    float s = 0.f;
    if (threadIdx.x == 0) {
        #pragma unroll
        for (int w = 0; w < NW; ++w) s += scratch[w];
    }
    return s;  // valid on thread 0 only
}

// Batcher odd-even 8-sort (19 CEs) — independent of running list (ILP).
#define CE_(A, i, j) { unsigned lo_ = min(A[i], A[j]); A[j] = max(A[i], A[j]); A[i] = lo_; }
__device__ inline void sort8(unsigned s[8]) {
    CE_(s,0,1) CE_(s,2,3) CE_(s,4,5) CE_(s,6,7)
    CE_(s,0,2) CE_(s,1,3) CE_(s,4,6) CE_(s,5,7)
    CE_(s,1,2) CE_(s,5,6)
    CE_(s,0,4) CE_(s,1,5) CE_(s,2,6) CE_(s,3,7)
    CE_(s,2,4) CE_(s,3,5)
    CE_(s,1,2) CE_(s,3,4) CE_(s,5,6)
}
// a (asc) := lowest-8 of union(a asc, s asc), sorted. Half-clean + bitonic merge.
__device__ inline void merge_top8(unsigned a[8], const unsigned s[8]) {
    #pragma unroll
    for (int i = 0; i < 8; ++i) a[i] = min(a[i], s[7 - i]);  // bitonic, lowest 8
    CE_(a,0,4) CE_(a,1,5) CE_(a,2,6) CE_(a,3,7)
    CE_(a,0,2) CE_(a,1,3) CE_(a,4,6) CE_(a,5,7)
    CE_(a,0,1) CE_(a,2,3) CE_(a,4,5) CE_(a,6,7)
}

// bf16 hi/lo split helpers (truncation; residual captures 8 more mantissa bits)
__device__ inline short hi16(float v) { return (short)(__float_as_uint(v) >> 16); }
__device__ inline float residual(float v) {
    return v - __uint_as_float(__float_as_uint(v) & 0xFFFF0000u);
}
__device__ inline unsigned pk2(short a, short b) {
    return (unsigned)(unsigned short)a | ((unsigned)(unsigned short)b << 16);
}
#define BF16_ONE ((short)0x3F80)

// ---------------------------------------------------------------------------
__global__ __launch_bounds__(256, 6) void mega_kernel(const float* __restrict__ src,
                                                      const float* __restrict__ dp_all,
                                                      const float* __restrict__ tp,
                                                      const float* __restrict__ drp,
                                                      const float* __restrict__ pw,
                                                      const float* __restrict__ rm,
                                                      float* __restrict__ out) {
    __shared__ uint4 smem4[1024];  // 16 KiB, shared by all roles
    const f32x4 zero4 = {0.f, 0.f, 0.f, 0.f};

    const int g = blockIdx.x / GRP_SZ;
    const int r = blockIdx.x % GRP_SZ;

    if (r < GRP_KNN) {  // ================= KNN + ARAP role (MFMA)
        const int knn_id = g * GRP_KNN + r;  // 0..1023
        uint4* alds = smem4;  // A-frags: [tile(32)][quad(2)][m(16)] uint4
        const int b   = knn_id / (N_ / 16);
        const int qt0 = (knn_id % (N_ / 16)) * 16;  // 16 queries/block
        const float* sb = src + (size_t)b * N_ * 3;

        const int wid  = __builtin_amdgcn_readfirstlane(threadIdx.x >> 6);
        const int lane = threadIdx.x & 63;
        const int n    = lane & 15;   // query col (and A-row m for staging reads)
        const int quad = lane >> 4;
        const int rbase = quad * 4;   // D-row base (candidate offset in tile)
        const int qid  = qt0 + n;

        // B-frag: this lane's query, hi/lo split; |q|^2 injected at k14/k15.
        bf16x8 bfrag = (bf16x8)(short)0;
        {
            float x = sb[3 * qid], y = sb[3 * qid + 1], z = sb[3 * qid + 2];
            float q2 = fmaf(x, x, fmaf(y, y, z * z));
            short hx = hi16(x), hy = hi16(y), hz = hi16(z);
            short lx = hi16(residual(x)), ly = hi16(residual(y)), lz = hi16(residual(z));
            if (quad == 0) bfrag = (bf16x8){hx, hy, hz, hx, hy, hz, BF16_ONE, BF16_ONE};
            else if (quad == 1) bfrag = (bf16x8){lx, ly, lz, lx, ly, lz,
                                                 hi16(q2), hi16(residual(q2))};
        }

        unsigned a[K_];
        #pragma unroll
        for (int p = 0; p < K_; ++p) a[p] = 0xFFFFFFFFu;

        for (int w = 0; w < N_ / CWIN; ++w) {  // 8 windows of 512 candidates
            __syncthreads();
            // Stage A-frags (2 candidates/thread, consecutive -> conflict-free).
            #pragma unroll
            for (int rr = 0; rr < 2; ++rr) {
                int jloc = rr * 256 + threadIdx.x;
                int jg = w * CWIN + jloc;
                float x = sb[3 * jg], y = sb[3 * jg + 1], z = sb[3 * jg + 2];
                float p2 = fmaf(x, x, fmaf(y, y, z * z));
                float mx = -2.f * x, my = -2.f * y, mz = -2.f * z;
                short mhx = hi16(mx), mhy = hi16(my), mhz = hi16(mz);
                short mlx = hi16(residual(mx)), mly = hi16(residual(my)), mlz = hi16(residual(mz));
                uint4 f0 = make_uint4(pk2(mhx, mhy), pk2(mhz, mlx), pk2(mly, mlz),
                                      pk2(hi16(p2), hi16(residual(p2))));
                uint4 f1 = make_uint4(f0.x, f0.y, f0.z, pk2(BF16_ONE, BF16_ONE));
                int tile = jloc >> 4, m = jloc & 15;
                alds[tile * 32 + m]      = f0;  // k0-7 slice
                alds[tile * 32 + 16 + m] = f1;  // k8-15 slice
            }
            __syncthreads();

            // This wave's quarter: tiles wid*8 .. wid*8+7 (batches of 2 tiles).
            #pragma unroll
            for (int bt = 0; bt < 4; ++bt) {
                unsigned s8[8];
                #pragma unroll
                for (int h = 0; h < 2; ++h) {
                    const int tile = wid * 8 + bt * 2 + h;
                    const int tbg  = w * CWIN + tile * 16;  // 16-aligned
                    bf16x8 af = (bf16x8)(short)0;
                    if (quad < 2) {
                        union { uint4 u; bf16x8 v; } cv;
                        cv.u = alds[tile * 32 + quad * 16 + n];
                        af = cv.v;
                    }
                    f32x4 d = __builtin_amdgcn_mfma_f32_16x16x32_bf16(af, bfrag, zero4, 0, 0, 0);
                    #pragma unroll
                    for (int rr = 0; rr < 4; ++rr)  // idx bits (0-11) disjoint from tbg
                        s8[h * 4 + rr] = (__float_as_uint(d[rr]) & 0xFFFFF000u)
                                         | (unsigned)(tbg | (rbase + rr));
                    if (tbg == qt0) {  // wave-uniform: the one self-overlap tile
                        #pragma unroll
                        for (int rr = 0; rr < 4; ++rr)
                            if (rbase + rr == n) s8[h * 4 + rr] = 0xFFFFFFFFu;
                    }
                }
                sort8(s8);
                merge_top8(a, s8);
            }
        }

        // Fold the 4 row-quads of each query column (lanes n, n+16, n+32, n+48).
        #pragma unroll
        for (int mk = 16; mk <= 32; mk <<= 1) {
            unsigned t[8];
            #pragma unroll
            for (int e = 0; e < K_; ++e) t[e] = __shfl_xor(a[e], mk, 64);
            merge_top8(a, t);
        }

        // Cross-wave merge (4 partial lists per query) + publish indices.
        __syncthreads();  // A-frag reads done; reuse LDS
        unsigned* sm = (unsigned*)smem4;          // [wave*16+q]*9+e  (<576)
        unsigned* nidx = (unsigned*)smem4 + 1024; // 128 entries
        if (lane < 16) {
            #pragma unroll
            for (int e = 0; e < K_; ++e) sm[(wid * 16 + n) * 9 + e] = a[e];
        }
        __syncthreads();
        if (threadIdx.x < 16) {
            const int q = threadIdx.x;
            unsigned md[K_];
            #pragma unroll
            for (int e = 0; e < K_; ++e) md[e] = sm[q * 9 + e];
            #pragma unroll
            for (int wv = 1; wv < 4; ++wv) {
                unsigned t[8];
                #pragma unroll
                for (int e = 0; e < K_; ++e) t[e] = sm[(wv * 16 + q) * 9 + e];
                merge_top8(md, t);
            }
            #pragma unroll
            for (int e = 0; e < K_; ++e) nidx[q * 8 + e] = md[e] & 0xFFFu;
        }
        __syncthreads();

        // Fused ARAP: 128 threads = 16 queries x 8 neighbors, all 3 t stages.
        float acc = 0.f;
        if (threadIdx.x < 16 * K_) {
            const int q  = threadIdx.x >> 3;
            const int qi = qt0 + q;
            const int j  = (int)nidx[threadIdx.x];
            float sx = sb[3 * qi], sy = sb[3 * qi + 1], sz = sb[3 * qi + 2];
            float ex = sb[3 * j] - sx, ey = sb[3 * j + 1] - sy, ez = sb[3 * j + 2] - sz;
            float sd = sqrtf(fmaf(ex, ex, fmaf(ey, ey, ez * ez)) + 1e-5f);
            #pragma unroll
            for (int t = 0; t < T_; ++t) {
                const float* dpb = dp_all + ((size_t)(t * B_ + b)) * N_ * 3;
                float dx = dpb[3 * j] - dpb[3 * qi];
                float dy = dpb[3 * j + 1] - dpb[3 * qi + 1];
                float dz = dpb[3 * j + 2] - dpb[3 * qi + 2];
                float dd = sqrtf(fmaf(dx, dx, fmaf(dy, dy, dz * dz)) + 1e-5f);
                float df = dd - sd;
                acc = fmaf(df, df, acc);
            }
        }
        float s = block_reduce<4>(acc, (float*)smem4);
        if (threadIdx.x == 0) atomicAdd(out, s * (1.0f / B_));

    } else if (r < GRP_KNN + GRP_CH) {  // ================= chamfer role (MFMA)
        const int cb = g * GRP_CH + (r - GRP_KNN);  // 0..383
        uint4* alds = smem4;
        const int tbd  = cb >> 4;     // ((t*B+b)*2+dir)
        const int slab = cb & 15;     // 256-query slab
        const int dir = tbd & 1;
        const int tb  = tbd >> 1;
        const int b = tb % B_, t = tb / B_;

        const float* dpb = dp_all + ((size_t)(t * B_ + b)) * N_ * 3;
        const float* tpb = tp + (size_t)b * N_ * 3;
        const float* cbase = dir ? dpb : tpb;  // candidates
        const float* qbase = dir ? tpb : dpb;  // queries

        const int lane = threadIdx.x & 63;
        const int wave = threadIdx.x >> 6;
        const int quad = lane >> 4;
        const int n    = lane & 15;

        bf16x8 bfrag[4];
        float  q2r[4];
        #pragma unroll
        for (int s = 0; s < 4; ++s) {
            int qid = slab * 256 + wave * 64 + s * 16 + n;
            float x = qbase[3 * qid], y = qbase[3 * qid + 1], z = qbase[3 * qid + 2];
            q2r[s] = fmaf(x, x, fmaf(y, y, z * z));
            short hx = hi16(x), hy = hi16(y), hz = hi16(z);
            short lx = hi16(residual(x)), ly = hi16(residual(y)), lz = hi16(residual(z));
            if (quad == 0)
                bfrag[s] = (bf16x8){hx, hy, hz, hx, hy, hz, BF16_ONE, BF16_ONE};
            else if (quad == 1)
                bfrag[s] = (bf16x8){lx, ly, lz, lx, ly, lz, 0, 0};
            else
                bfrag[s] = (bf16x8)(short)0;
        }

        float run[4] = {3.4e38f, 3.4e38f, 3.4e38f, 3.4e38f};

        for (int w = 0; w < N_ / CWIN; ++w) {
            __syncthreads();
            #pragma unroll
            for (int rr = 0; rr < 2; ++rr) {
                int jloc = rr * 256 + threadIdx.x;  // consecutive -> conflict-free
                int jg = w * CWIN + jloc;
                float x = cbase[3 * jg], y = cbase[3 * jg + 1], z = cbase[3 * jg + 2];
                float p2 = fmaf(x, x, fmaf(y, y, z * z));
                float mx = -2.f * x, my = -2.f * y, mz = -2.f * z;
                short mhx = hi16(mx), mhy = hi16(my), mhz = hi16(mz);
                short mlx = hi16(residual(mx)), mly = hi16(residual(my)), mlz = hi16(residual(mz));
                uint4 f0 = make_uint4(pk2(mhx, mhy), pk2(mhz, mlx), pk2(mly, mlz),
                                      pk2(hi16(p2), hi16(residual(p2))));
                uint4 f1 = make_uint4(f0.x, f0.y, f0.z, 0u);
                int tile = jloc >> 4, m = jloc & 15;
                alds[tile * 32 + m]      = f0;
                alds[tile * 32 + 16 + m] = f1;
            }
            __syncthreads();

            #pragma unroll 4
            for (int tile = 0; tile < CWIN / 16; ++tile) {
                bf16x8 af = (bf16x8)(short)0;
                if (quad < 2) {
                    union { uint4 u; bf16x8 v; } cv;
                    cv.u = alds[tile * 32 + quad * 16 + n];
                    af = cv.v;
                }
                #pragma unroll
                for (int s = 0; s < 4; ++s) {
                    f32x4 d = __builtin_amdgcn_mfma_f32_16x16x32_bf16(af, bfrag[s], zero4, 0, 0, 0);
                    float r3 = fminf(fminf(d[0], d[1]), d[2]);
                    run[s] = fminf(fminf(run[s], r3), d[3]);
                }
            }
        }

        float vsum = 0.f;
        #pragma unroll
        for (int s = 0; s < 4; ++s) {
            float rr = run[s];
            rr = fminf(rr, __shfl_xor(rr, 32));
            rr = fminf(rr, __shfl_xor(rr, 16));
            if (lane < 16) vsum += rr + q2r[s];
        }
        __syncthreads();
        float ssum = block_reduce<4>(vsum, (float*)smem4);
        if (threadIdx.x == 0) atomicAdd(out, ssum * (0.5f / B_));

    } else {  // ================= pd + sp + tran role
        const int PD_N = T_ * B_ * N_ * 3;
        const int SP_N = T_ * B_ * N_;
        const int stride = GROUPS * 256;
        const int gid = g * 256 + threadIdx.x;
        float apd = 0.f;
        for (int i = gid; i < PD_N; i += stride) {
            float d = drp[i] - dp_all[i];
            apd = fmaf(d, d, apd);
        }
        float asp = 0.f;
        for (int i = gid; i < SP_N; i += stride) asp += fabsf(pw[i]);
        float atr = 0.f;
        if (gid < T_ * B_ * 3) {
            int t = gid / (B_ * 3);
            int b = (gid / 3) % B_;
            int rr = gid % 3;
            float v = rm[t * B_ * 16 + b * 16 + rr * 4 + 3];
            atr = v * v;
        }
        float acc = apd * (1.0f / B_) + asp * (1.0f / (B_ * N_)) + atr * (1.0f / B_);
        float s = block_reduce<4>(acc, (float*)smem4);
        if (threadIdx.x == 0) atomicAdd(out, s);
    }
}

// ---------------------------------------------------------------------------
extern "C" void kernel_launch(void* const* d_in, const int* in_sizes, int n_in,
                              void* d_out, int out_size, void* d_ws, size_t ws_size,
                              hipStream_t stream) {
    const float* pw  = (const float*)d_in[1];
    const float* drp = (const float*)d_in[2];
    const float* dp  = (const float*)d_in[3];
    const float* rm  = (const float*)d_in[4];
    const float* sp  = (const float*)d_in[5];
    const float* tp  = (const float*)d_in[6];
    float* out = (float*)d_out;

    hipMemsetAsync(out, 0, sizeof(float), stream);
    mega_kernel<<<GROUPS * GRP_SZ, 256, 0, stream>>>(sp, dp, tp, drp, pw, rm, out);
}